// Round 12
// baseline (220.466 us; speedup 1.0000x reference)
//
#include <hip/hip_runtime.h>
#include <hip/hip_bf16.h>

using short8 = __attribute__((ext_vector_type(8))) short;
using f32x4  = __attribute__((ext_vector_type(4))) float;
using u32x4  = __attribute__((ext_vector_type(4))) unsigned int;

#define DDIM 512
#define NROWS 1024
#define CCLS 100000
#define NCT 782            // c-tiles of 128
#define CPAD (NCT * 128)   // 100096 padded classes
#define GRID_BLOCKS 512    // 2/CU resident (66KB LDS), persistent XCD-windowed

#define XSCALE 92.33248261689366f      // 64 * log2(e): acc = XSCALE * cos
#define INV_XSCALE 0.010830424696358f  // ln2/64: cos = acc * INV_XSCALE

__device__ inline unsigned int f2bf(float f) {
    unsigned int u = __float_as_uint(f);
    u += 0x7FFFu + ((u >> 16) & 1u);
    return u >> 16;
}

__device__ inline unsigned int pk2(float x, float y) {
    unsigned int r;
    asm("v_cvt_pk_bf16_f32 %0, %1, %2" : "=v"(r) : "v"(x), "v"(y));
    return r;
}

__device__ inline void gload_lds16(const void* g, void* l) {
    __builtin_amdgcn_global_load_lds(
        (const __attribute__((address_space(1))) void*)g,
        (__attribute__((address_space(3))) void*)l, 16, 0, 0);
}

// ------- kernel 1: normalize x rows -> bf16, scaled by 64*log2(e) ----------
__global__ __launch_bounds__(256) void norm_x(const float* __restrict__ x,
                                              unsigned short* __restrict__ xn) {
    const int row = blockIdx.x;
    const int tid = threadIdx.x;
    float2 v = *(const float2*)(x + (size_t)row * DDIM + tid * 2);
    float ss = v.x * v.x + v.y * v.y;
#pragma unroll
    for (int m = 1; m < 64; m <<= 1) ss += __shfl_xor(ss, m);
    __shared__ float wsum[4];
    if ((tid & 63) == 0) wsum[tid >> 6] = ss;
    __syncthreads();
    float inv = XSCALE / sqrtf(wsum[0] + wsum[1] + wsum[2] + wsum[3]);
    unsigned int packed = f2bf(v.x * inv) | (f2bf(v.y * inv) << 16);
    ((unsigned int*)xn)[(size_t)row * (DDIM / 2) + tid] = packed;
}

// ------- kernel 2: W -> PRE-NORMALIZED bf16 (one wave per row) --------------
__global__ __launch_bounds__(256) void norm_w_cvt(const float* __restrict__ W,
                                                  unsigned short* __restrict__ Wbf) {
    const int row  = blockIdx.x * 4 + (threadIdx.x >> 6);
    const int lane = threadIdx.x & 63;
    if (row < CCLS) {
        const float4* p = (const float4*)(W + (size_t)row * DDIM + lane * 8);
        float4 a = p[0], b = p[1];
        float ss = a.x*a.x + a.y*a.y + a.z*a.z + a.w*a.w
                 + b.x*b.x + b.y*b.y + b.z*b.z + b.w*b.w;
#pragma unroll
        for (int m = 1; m < 64; m <<= 1) ss += __shfl_xor(ss, m);
        float inv = (ss > 0.0f) ? (1.0f / sqrtf(ss)) : 0.0f;
        u32x4 u = { pk2(a.x * inv, a.y * inv), pk2(a.z * inv, a.w * inv),
                    pk2(b.x * inv, b.y * inv), pk2(b.z * inv, b.w * inv) };
        *(u32x4*)(Wbf + (size_t)row * DDIM + lane * 8) = u;
    } else {
        *(u32x4*)(Wbf + (size_t)row * DDIM + lane * 8) = u32x4{0u, 0u, 0u, 0u};
    }
}

// ---------------- kernel 3: GEMM + exp-rowsum + target ----------------------
// 128x128 tile, BK=64, 4 waves (2x2), acc[4][4] (64 AGPR), 16x16x32 MFMA.
// DOUBLE-BUFFERED pure-DMA staging (T3 minimum 2-phase): stage(k+1) issued
// BEFORE compute(k); ONE barrier per k-step drains the in-flight DMA after
// compute covered it. At k=7 the NEXT pair's k0 is staged -> DMA latency is
// never exposed, even across pairs (epilogue also overlaps the drain).
// Epilogue: acc = 92.33*cos directly (prenorm W, scaled xn) -> one exp2f per
// element, no winv. LDS 66KB -> 2 blocks/CU.
__global__ __launch_bounds__(256, 2) void arc_gemm(
    const unsigned short* __restrict__ xn,   // [1024][512] bf16 (x 92.33/||x||)
    const unsigned short* __restrict__ Wbf,  // [CPAD][512] bf16 (W/||W||, 0-pad)
    const int* __restrict__ labels,          // [1024]
    float* __restrict__ rowsum,              // [1024] (pre-zeroed)
    float* __restrict__ tcos)                // [1024]
{
    __shared__ __align__(16) unsigned short lsA[2][128 * 64]; // 2 x 16 KB
    __shared__ __align__(16) unsigned short lsW[2][128 * 64]; // 2 x 16 KB
    __shared__ float lrow[128];
    __shared__ int   llab[128];

    const int tid  = threadIdx.x;
    const int lane = tid & 63;
    const int wid  = tid >> 6;
    const int wr   = wid >> 1, wc = wid & 1;
    const int q    = lane >> 4;
    const int fr   = lane & 15;

    // DMA geometry: inst it covers rows it*32..+31; dest linear, source column
    // pre-swizzled by row&7 (rule #21) -> conflict-free 16-row ds_read_b128.
    const int grow = tid >> 3;
    const int gcol = ((tid & 7) ^ (grow & 7)) * 8;   // bf16 units

    const int x    = blockIdx.x & 7;
    const int sidx = blockIdx.x >> 3;                // 0..63 in XCD window
    const int nct  = (NCT - 1 - x) / 8 + 1;
    const int npairs = nct * 8;
    const int STRIDE = GRID_BLOCKS / 8;              // 64

    auto stage = [&](int b, int c0s, int m0s, int k0) {
#pragma unroll
        for (int it = 0; it < 4; ++it)
            gload_lds16(xn + (size_t)(m0s + it * 32 + grow) * DDIM + k0 + gcol,
                        (char*)lsA[b] + (it * 256 + tid) * 16);
#pragma unroll
        for (int it = 0; it < 4; ++it)
            gload_lds16(Wbf + (size_t)(c0s + it * 32 + grow) * DDIM + k0 + gcol,
                        (char*)lsW[b] + (it * 256 + tid) * 16);
    };

    int cur = 0;
    // prologue: stage first pair's k0
    if (sidx < npairs) {
        int ct0 = x + 8 * (sidx >> 3), mt0 = sidx & 7;
        stage(0, ct0 * 128, mt0 * 128, 0);
    }

#pragma unroll 1
    for (int p = sidx; p < npairs; p += STRIDE) {
        const int c0 = (x + 8 * (p >> 3)) * 128;
        const int m0 = (p & 7) * 128;
        const int pn = p + STRIDE;
        const int cn0 = (pn < npairs) ? (x + 8 * (pn >> 3)) * 128 : -1;
        const int mn0 = (pn < npairs) ? (pn & 7) * 128 : 0;

        __syncthreads();   // drain k0 DMA (first pair) / ordering
        if (tid < 128) { lrow[tid] = 0.0f; llab[tid] = labels[m0 + tid]; }

        f32x4 acc[4][4];
#pragma unroll
        for (int i = 0; i < 4; ++i)
#pragma unroll
            for (int j = 0; j < 4; ++j) acc[i][j] = (f32x4)(0.0f);

#pragma unroll 1
        for (int k = 0; k < 8; ++k) {
            // issue next tile's DMA into the other buffer BEFORE compute
            if (k < 7)            stage(cur ^ 1, c0, m0, (k + 1) * 64);
            else if (cn0 >= 0)    stage(cur ^ 1, cn0, mn0, 0);

            // compute current buffer (pure LDS + MFMA)
#pragma unroll
            for (int ks = 0; ks < 2; ++ks) {
                short8 af[4], bg[4];
#pragma unroll
                for (int i = 0; i < 4; ++i) {
                    int r = wr * 64 + i * 16 + fr;
                    af[i] = *(const short8*)((const char*)lsA[cur]
                            + r * 128 + (((ks * 4 + q) ^ (r & 7)) << 4));
                }
#pragma unroll
                for (int j = 0; j < 4; ++j) {
                    int rc = wc * 64 + j * 16 + fr;
                    bg[j] = *(const short8*)((const char*)lsW[cur]
                            + rc * 128 + (((ks * 4 + q) ^ (rc & 7)) << 4));
                }
#pragma unroll
                for (int i = 0; i < 4; ++i)
#pragma unroll
                    for (int j = 0; j < 4; ++j)
                        acc[i][j] = __builtin_amdgcn_mfma_f32_16x16x32_bf16(
                            af[i], bg[j], acc[i][j], 0, 0, 0);
            }
            __syncthreads();   // drains DMA(k+1); buf reads complete
            cur ^= 1;
        }
        // buf 'cur' now holds next pair's k0 (staged at k=7, drained)

        // ---- epilogue: acc = 92.33*cos; e = exp2(acc); reduce; target ----
        int cj[4];
#pragma unroll
        for (int j = 0; j < 4; ++j) cj[j] = c0 + wc * 64 + j * 16 + fr;
#pragma unroll
        for (int i = 0; i < 4; ++i) {
#pragma unroll
            for (int v = 0; v < 4; ++v) {
                const int rl  = wr * 64 + i * 16 + q * 4 + v;
                const int lab = llab[rl];
                float sm = 0.0f;
#pragma unroll
                for (int j = 0; j < 4; ++j) {
                    float a = acc[i][j][v];
                    sm += (cj[j] < CCLS) ? exp2f(a) : 0.0f;
                    if (cj[j] == lab) tcos[m0 + rl] = a * INV_XSCALE;
                }
                sm += __shfl_xor(sm, 1);
                sm += __shfl_xor(sm, 2);
                sm += __shfl_xor(sm, 4);
                sm += __shfl_xor(sm, 8);
                if (fr == 0) atomicAdd(&lrow[rl], sm);
            }
        }
        __syncthreads();
        if (tid < 128) atomicAdd(&rowsum[m0 + tid], lrow[tid]);
        // same-tid lrow/llab rewrite next pair; reads already done (barrier)
    }
}

// ---------------- kernel 4: final loss ----------------
__global__ __launch_bounds__(256) void arc_final(const float* __restrict__ rowsum,
                                                 const float* __restrict__ tcos,
                                                 float* __restrict__ out) {
    const int tid = threadIdx.x;
    const float cosM = 0.87758256189037271612f;  // cos(0.5)
    const float sinM = 0.47942553860420300027f;  // sin(0.5)
    float L = 0.0f;
    for (int n = tid; n < NROWS; n += 256) {
        float tc  = tcos[n];
        float tcl = fminf(fmaxf(tc, -1.0f + 1e-7f), 1.0f - 1e-7f);
        float num = 64.0f * (tcl * cosM - sinM * sqrtf(fmaxf(0.0f, 1.0f - tcl * tcl)));
        float den = __expf(num) + rowsum[n] - __expf(64.0f * tc);
        L += num - logf(den);
    }
    __shared__ float red[256];
    red[tid] = L;
    __syncthreads();
    for (int s = 128; s > 0; s >>= 1) {
        if (tid < s) red[tid] += red[tid + s];
        __syncthreads();
    }
    if (tid == 0) out[0] = -(red[0] / (float)NROWS);
}

// ---------------- launch ----------------
extern "C" void kernel_launch(void* const* d_in, const int* in_sizes, int n_in,
                              void* d_out, int out_size, void* d_ws, size_t ws_size,
                              hipStream_t stream) {
    const float* x      = (const float*)d_in[0];
    const float* W      = (const float*)d_in[1];
    const int*   labels = (const int*)d_in[2];
    float* out = (float*)d_out;
    char*  ws  = (char*)d_ws;

    const size_t WBF_BYTES = (size_t)CPAD * DDIM * 2;   // 102,498,304
    unsigned short* xn  = (unsigned short*)(ws);                     // 1 MB
    unsigned short* Wbf = (unsigned short*)(ws + 1048576);
    const size_t tail   = 1048576 + WBF_BYTES;

    float* rowsum = (float*)(ws + tail);
    float* tcos   = (float*)(ws + tail + 4096);

    (void)hipMemsetAsync(rowsum, 0, NROWS * sizeof(float), stream);

    norm_x<<<NROWS, 256, 0, stream>>>(x, xn);
    norm_w_cvt<<<CPAD / 4, 256, 0, stream>>>(W, Wbf);

    arc_gemm<<<GRID_BLOCKS, 256, 0, stream>>>(xn, Wbf, labels, rowsum, tcos);

    arc_final<<<1, 256, 0, stream>>>(rowsum, tcos, out);
}